// Round 4
// baseline (345.377 us; speedup 1.0000x reference)
//
#include <hip/hip_runtime.h>
#include <hip/hip_bf16.h>

#define HH 96
#define WW 96
#define CC 128
#define C2 256
#define PLANE (HH*WW)          // 9216
#define KTOT 1152              // 128 ic * 9 taps, natural [ic][tap] order
#define PXT 64                 // pixels per K2 block
#define NSEG (PLANE/PXT)       // 144
#define NGRP 6                 // K1 channel groups (partials in d_out ch 0..107)

typedef __attribute__((ext_vector_type(8))) short bf16x8;
typedef __attribute__((ext_vector_type(4))) float f32x4;
typedef __attribute__((ext_vector_type(4))) unsigned int u32x4;

// XOR-swizzle within a 128B row: byte bits 4..6 ^= (row&7)
__device__ __forceinline__ int swz(int row, int byte_in_row) {
    return row * 128 + (byte_in_row ^ ((row & 7) << 4));
}

// ---------------- Kernel 0: w_def fp32 -> bf16 (natural layout) --------------------
__global__ __launch_bounds__(256) void wcvt_kernel(const float* __restrict__ w,
                                                   unsigned short* __restrict__ o)
{
    int i = blockIdx.x * 256 + threadIdx.x;
    if (i < CC * KTOT)
        o[i] = __bfloat16_as_ushort(__float2bfloat16(w[i]));
}

// ---------------- Kernel 1: offset conv (partials into d_out ch 0..107) ------------
// grid: 4 (b) * 36 (16x16 tiles) * 6 (c-groups) = 864 blocks, 256 threads
__global__ __launch_bounds__(256) void offset_conv_kernel(
    const float* __restrict__ lr, const float* __restrict__ hr,
    const float* __restrict__ w_off, float* __restrict__ outp)
{
    __shared__ float tile[2][4][324];
    const int bid = blockIdx.x;
    const int q   = bid % NGRP;
    const int t   = bid / NGRP;
    const int b   = t / 36;
    const int rr  = t % 36;
    const int h0  = (rr / 6) * 16;
    const int w0  = (rr % 6) * 16;
    const int tid = threadIdx.x;
    const int py  = tid >> 4;
    const int px  = tid & 15;

    const int c0 = (C2 * q) / NGRP, c1 = (C2 * (q + 1)) / NGRP;
    const float* srcp = (q < 3) ? lr : hr;   // group boundaries align with 128
    const int cofs = (q < 3) ? 0 : CC;

    int gy0 = h0 - 1 + tid / 18, gx0 = w0 - 1 + tid % 18;
    bool ok0 = (unsigned)gy0 < (unsigned)HH && (unsigned)gx0 < (unsigned)WW;
    int off0 = gy0 * WW + gx0;
    int j1 = tid + 256;
    int gy1 = h0 - 1 + j1 / 18, gx1 = w0 - 1 + j1 % 18;
    bool ok1 = (j1 < 324) && (unsigned)gy1 < (unsigned)HH && (unsigned)gx1 < (unsigned)WW;
    int off1 = gy1 * WW + gx1;

    float acc[18];
#pragma unroll
    for (int oc = 0; oc < 18; ++oc) acc[oc] = 0.f;

    float pr[4][2];
    {
        int S0 = min(4, c1 - c0);
        for (int s = 0; s < S0; ++s) {
            const float* pn = srcp + (size_t)(b * CC + c0 + s - cofs) * PLANE;
            pr[s][0] = ok0 ? pn[off0] : 0.f;
            pr[s][1] = ok1 ? pn[off1] : 0.f;
        }
    }

    int buf = 0;
    for (int cg = c0; cg < c1; cg += 4, buf ^= 1) {
        const int Scur = min(4, c1 - cg);
        for (int s = 0; s < Scur; ++s) {
            tile[buf][s][tid] = pr[s][0];
            if (j1 < 324) tile[buf][s][j1] = pr[s][1];
        }
        __syncthreads();
        const int Snext = min(4, c1 - (cg + 4));
        for (int s = 0; s < Snext; ++s) {
            const float* pn = srcp + (size_t)(b * CC + cg + 4 + s - cofs) * PLANE;
            pr[s][0] = ok0 ? pn[off0] : 0.f;
            pr[s][1] = ok1 ? pn[off1] : 0.f;
        }
        for (int s = 0; s < Scur; ++s) {
            float tv[9];
#pragma unroll
            for (int ky = 0; ky < 3; ++ky)
#pragma unroll
                for (int kx = 0; kx < 3; ++kx)
                    tv[ky*3+kx] = tile[buf][s][(py+ky)*18 + px + kx];
            const int c = cg + s;
#pragma unroll
            for (int oc = 0; oc < 18; ++oc) {
                const float* wp = w_off + (size_t)(oc * C2 + c) * 9;   // uniform -> s_load
#pragma unroll
                for (int tap = 0; tap < 9; ++tap)
                    acc[oc] = fmaf(wp[tap], tv[tap], acc[oc]);
            }
        }
    }
#pragma unroll
    for (int oc = 0; oc < 18; ++oc)
        outp[((size_t)(b*CC + q*18 + oc)) * PLANE + (h0+py)*WW + (w0+px)] = acc[oc];
}

// ---------------- Kernel 2: deformable conv, bf16 MFMA, [ic][tap] K-order ----------
// grid: 4 (b) * 144 segs = 576 blocks, 512 threads (8 waves, 16 oc each)
__global__ __launch_bounds__(512, 4) void deform_mfma_kernel(
    const float* __restrict__ hr, const float* __restrict__ b_off,
    const unsigned short* __restrict__ wbf, const float* __restrict__ b_def,
    float* __restrict__ outp)
{
    __shared__ __align__(16) unsigned short wgt_lds[CC * 64];    // 16KB swizzled
    __shared__ __align__(16) unsigned short samp_lds[PXT * 64];  // 8KB swizzled
    __shared__ short4 gyo[9 * PXT];                 // precomputed linear offsets
    __shared__ __align__(16) float4 gwv[9 * PXT];   // masked bilinear weights
    __shared__ float bias_lds[CC];

    const int bid = blockIdx.x;
    const int b   = bid / NSEG;
    const int seg = bid % NSEG;
    const int hw0 = seg * PXT;
    const int tid = threadIdx.x;

    // ---- Phase A: geometry from offset partials (d_out ch 0..107) ----
    for (int t = tid; t < 9 * PXT; t += 512) {
        int kk = t >> 6;
        int p2 = t & 63;
        int hw = hw0 + p2;
        int h2 = hw / WW, w2 = hw - h2 * WW;
        float offy = b_off[2*kk], offx = b_off[2*kk + 1];
#pragma unroll
        for (int q = 0; q < NGRP; ++q) {
            offy += outp[((size_t)(b*CC + q*18 + 2*kk    )) * PLANE + hw];
            offx += outp[((size_t)(b*CC + q*18 + 2*kk + 1)) * PLANE + hw];
        }
        float sy = (float)h2 + (float)(kk/3 - 1) + offy;
        float sx = (float)w2 + (float)(kk%3 - 1) + offx;
        float y0f = floorf(sy), x0f = floorf(sx);
        float dy = sy - y0f,   dx = sx - x0f;
        int y0 = (int)y0f, x0 = (int)x0f;
        int y1 = y0 + 1,   x1 = x0 + 1;
        bool y0v = (unsigned)y0 < (unsigned)HH, y1v = (unsigned)y1 < (unsigned)HH;
        bool x0v = (unsigned)x0 < (unsigned)WW, x1v = (unsigned)x1 < (unsigned)WW;
        float ody = 1.f - dy, odx = 1.f - dx;
        float4 wv;
        wv.x = (y0v && x0v) ? ody*odx : 0.f;
        wv.y = (y0v && x1v) ? ody*dx  : 0.f;
        wv.z = (y1v && x0v) ? dy*odx  : 0.f;
        wv.w = (y1v && x1v) ? dy*dx   : 0.f;
        int y0c = min(max(y0, 0), HH-1), y1c = min(max(y1, 0), HH-1);
        int x0c = min(max(x0, 0), WW-1), x1c = min(max(x1, 0), WW-1);
        short4 o4;
        o4.x = (short)(y0c*WW + x0c);
        o4.y = (short)(y0c*WW + x1c);
        o4.z = (short)(y1c*WW + x0c);
        o4.w = (short)(y1c*WW + x1c);
        gyo[t] = o4;
        gwv[t] = wv;
    }
    if (tid < CC) bias_lds[tid] = b_def[tid];
    __syncthreads();

    const int px   = tid & 63;
    const int icq  = tid >> 6;       // wave id 0..7; owns k-slot icq*8..icq*8+7
    const int lane = tid & 63;
    const int oc0  = icq * 16;
    const int l15  = lane & 15;
    const int l4   = lane >> 4;

    f32x4 acc[4];
#pragma unroll
    for (int nf = 0; nf < 4; ++nf) acc[nf] = (f32x4){0.f, 0.f, 0.f, 0.f};

    const float* hrb = hr + (size_t)b * CC * PLANE;

    float vv[32];
    int gg[8];
    unsigned sp[4];
    u32x4 wpre[2];

    // issue the gathers for chunk CH (64 consecutive k in [ic][tap] order)
#define ISSUE(CH) { \
    int kbase = (CH)*64 + icq*8; \
    _Pragma("unroll") \
    for (int j = 0; j < 8; ++j) { \
        int k = kbase + j; \
        int ic = (int)((unsigned)k / 9u); \
        int tap = k - ic*9; \
        int g2 = tap*PXT + px; \
        gg[j] = g2; \
        short4 o4 = gyo[g2]; \
        const float* p = hrb + (size_t)ic * PLANE; \
        vv[4*j+0] = p[o4.x]; vv[4*j+1] = p[o4.y]; \
        vv[4*j+2] = p[o4.z]; vv[4*j+3] = p[o4.w]; \
    } }

#define WLOAD(CH) { \
    _Pragma("unroll") \
    for (int j2 = 0; j2 < 2; ++j2) { \
        int t2 = tid + j2*512; \
        int oc = t2 >> 3; int slot = t2 & 7; \
        wpre[j2] = *reinterpret_cast<const u32x4*>(wbf + (size_t)oc*KTOT + (CH)*64 + slot*8); \
    } }

    // bilinear-combine + pack (consumes vv)
#define FINISH() { \
    _Pragma("unroll") \
    for (int j = 0; j < 8; ++j) { \
        float4 w4 = gwv[gg[j]]; \
        float sv = fmaf(w4.x, vv[4*j+0], fmaf(w4.y, vv[4*j+1], \
                   fmaf(w4.z, vv[4*j+2], w4.w * vv[4*j+3]))); \
        unsigned us = (unsigned)__bfloat16_as_ushort(__float2bfloat16(sv)); \
        if (j & 1) sp[j>>1] |= us << 16; else sp[j>>1] = us; \
    } }

    // prologue: chunk 0 fully prefetched
    ISSUE(0); WLOAD(0); FINISH();

    for (int ch = 0; ch < 18; ++ch) {
        __syncthreads();   // prev MFMA done reading LDS
#pragma unroll
        for (int j2 = 0; j2 < 2; ++j2) {
            int t2 = tid + j2*512;
            int oc = t2 >> 3; int slot = t2 & 7;
            *reinterpret_cast<u32x4*>((char*)wgt_lds + swz(oc, slot*16)) = wpre[j2];
        }
        {
            u32x4 spv = {sp[0], sp[1], sp[2], sp[3]};
            *reinterpret_cast<u32x4*>((char*)samp_lds + swz(px, icq*16)) = spv;
        }
        __syncthreads();
        // prefetch chunk ch+1: issue gathers + weight loads (latency hides under MFMA)
        if (ch < 17) { ISSUE(ch+1); WLOAD(ch+1); }
        // MFMA on chunk ch
#pragma unroll
        for (int ks = 0; ks < 2; ++ks) {
            int kb = ks*64 + l4*16;
            bf16x8 afr = *reinterpret_cast<const bf16x8*>((char*)wgt_lds + swz(oc0 + l15, kb));
#pragma unroll
            for (int nf = 0; nf < 4; ++nf) {
                bf16x8 bfr = *reinterpret_cast<const bf16x8*>((char*)samp_lds + swz(nf*16 + l15, kb));
                acc[nf] = __builtin_amdgcn_mfma_f32_16x16x32_bf16(afr, bfr, acc[nf], 0, 0, 0);
            }
        }
        // combine gathered values after MFMA issued
        if (ch < 17) FINISH();
    }

    // ---- epilogue: bias + store ----
#pragma unroll
    for (int r = 0; r < 4; ++r) {
        int oc = oc0 + l4*4 + r;
        float bd = bias_lds[oc];
#pragma unroll
        for (int nf = 0; nf < 4; ++nf)
            outp[((size_t)(b*CC + oc)) * PLANE + hw0 + nf*16 + l15] = acc[nf][r] + bd;
    }
#undef ISSUE
#undef WLOAD
#undef FINISH
}

extern "C" void kernel_launch(void* const* d_in, const int* in_sizes, int n_in,
                              void* d_out, int out_size, void* d_ws, size_t ws_size,
                              hipStream_t stream)
{
    const float* lr    = (const float*)d_in[0];
    const float* hr    = (const float*)d_in[1];
    const float* w_off = (const float*)d_in[2];
    const float* b_off = (const float*)d_in[3];
    const float* w_def = (const float*)d_in[4];
    const float* b_def = (const float*)d_in[5];
    float* outp = (float*)d_out;
    unsigned short* wbf = (unsigned short*)d_ws;   // 288KB

    wcvt_kernel<<<(CC*KTOT + 255)/256, 256, 0, stream>>>(w_def, wbf);
    offset_conv_kernel<<<4*36*NGRP, 256, 0, stream>>>(lr, hr, w_off, outp);
    deform_mfma_kernel<<<4*NSEG, 512, 0, stream>>>(hr, b_off, wbf, b_def, outp);
}

// Round 5
// 325.184 us; speedup vs baseline: 1.0621x; 1.0621x over previous
//
#include <hip/hip_runtime.h>
#include <hip/hip_bf16.h>

#define HH 96
#define WW 96
#define CC 128
#define C2 256
#define PLANE (HH*WW)          // 9216
#define KTOT 1152
#define NGRP 6                 // K1 channel groups (partials in d_out ch 0..107)
#define GP 7                   // ic-planes per K2 group
#define NG 19                  // ceil(128/7) groups
#define KLG 64                 // padded k-slots per group (63 real + 1 pad)
#define ROWS 15                // staged rows per plane window
#define NCHK (GP*ROWS*24)      // 2520 16B-chunks of plane staging per group

typedef __attribute__((ext_vector_type(8))) short bf16x8;
typedef __attribute__((ext_vector_type(4))) float f32x4;
typedef __attribute__((ext_vector_type(4))) unsigned int u32x4;

__device__ __forceinline__ int swzb(int row, int byte_in_row) {
    return row * 128 + (byte_in_row ^ ((row & 7) << 4));
}

// ------------- Kernel 0: w_def fp32 -> bf16 padded [oc][group][64] -----------------
__global__ __launch_bounds__(256) void wcvt_kernel(const float* __restrict__ w,
                                                   unsigned short* __restrict__ o)
{
    int i = blockIdx.x * 256 + threadIdx.x;   // 128*19*64 = 155648
    if (i < CC * NG * KLG) {
        int oc = i / (NG * KLG);
        int r  = i - oc * (NG * KLG);
        int g  = r >> 6;
        int s  = r & 63;
        int k  = g * 63 + s;                  // natural k = ic*9 + tap
        float v = (s < 63 && k < KTOT) ? w[(size_t)oc * KTOT + k] : 0.f;
        o[i] = __bfloat16_as_ushort(__float2bfloat16(v));
    }
}

// ------------- Kernel 1: offset conv (partials into d_out ch 0..107) ---------------
// grid: 4 (b) * 36 (16x16 tiles) * 6 (c-groups) = 864 blocks, 256 threads
__global__ __launch_bounds__(256) void offset_conv_kernel(
    const float* __restrict__ lr, const float* __restrict__ hr,
    const float* __restrict__ w_off, float* __restrict__ outp)
{
    __shared__ float tile[2][324];
    const int bid = blockIdx.x;
    const int q   = bid % NGRP;
    const int t   = bid / NGRP;
    const int b   = t / 36;
    const int rr  = t % 36;
    const int h0  = (rr / 6) * 16;
    const int w0  = (rr % 6) * 16;
    const int tid = threadIdx.x;
    const int py  = tid >> 4;
    const int px  = tid & 15;

    const int c0 = (C2 * q) / NGRP, c1 = (C2 * (q + 1)) / NGRP;
    const float* srcp = (q < 3) ? lr : hr;
    const int cofs = (q < 3) ? 0 : CC;

    int gy0 = h0 - 1 + tid / 18, gx0 = w0 - 1 + tid % 18;
    bool ok0 = (unsigned)gy0 < (unsigned)HH && (unsigned)gx0 < (unsigned)WW;
    int off0 = gy0 * WW + gx0;
    int j1 = tid + 256;
    int gy1 = h0 - 1 + j1 / 18, gx1 = w0 - 1 + j1 % 18;
    bool ok1 = (j1 < 324) && (unsigned)gy1 < (unsigned)HH && (unsigned)gx1 < (unsigned)WW;
    int off1 = gy1 * WW + gx1;

    float acc[18];
#pragma unroll
    for (int oc = 0; oc < 18; ++oc) acc[oc] = 0.f;

    const float* pl = srcp + (size_t)(b * CC + c0 - cofs) * PLANE;
    float p0 = ok0 ? pl[off0] : 0.f;
    float p1 = ok1 ? pl[off1] : 0.f;

    for (int c = c0; c < c1; ++c) {
        float* tb = tile[c & 1];
        tb[tid] = p0;
        if (j1 < 324) tb[j1] = p1;
        __syncthreads();
        if (c + 1 < c1) {
            const float* pn = srcp + (size_t)(b * CC + c + 1 - cofs) * PLANE;
            p0 = ok0 ? pn[off0] : 0.f;
            p1 = ok1 ? pn[off1] : 0.f;
        }
        float tv[9];
#pragma unroll
        for (int ky = 0; ky < 3; ++ky)
#pragma unroll
            for (int kx = 0; kx < 3; ++kx)
                tv[ky*3+kx] = tb[(py+ky)*18 + px + kx];
#pragma unroll
        for (int oc = 0; oc < 18; ++oc) {
            const float* wp = w_off + (size_t)(oc * C2 + c) * 9;   // uniform -> s_load
#pragma unroll
            for (int tap = 0; tap < 9; ++tap)
                acc[oc] = fmaf(wp[tap], tv[tap], acc[oc]);
        }
    }
#pragma unroll
    for (int oc = 0; oc < 18; ++oc)
        outp[((size_t)(b*CC + q*18 + oc)) * PLANE + (h0+py)*WW + (w0+px)] = acc[oc];
}

// ------------- Kernel 2: deformable conv, LDS-staged bilinear + bf16 MFMA ----------
// grid: 4 (b) * 96 (rows) = 384 blocks, 768 threads (12 waves)
__global__ __launch_bounds__(768, 4) void deform_mfma_kernel(
    const float* __restrict__ hr, const float* __restrict__ b_off,
    const unsigned short* __restrict__ wpad, const float* __restrict__ b_def,
    float* __restrict__ outp)
{
    __shared__ __align__(16) float planes_lds[GP * ROWS * WW];      // 40320B
    __shared__ __align__(16) unsigned short wgt_lds[CC * KLG];      // 16384B swizzled
    __shared__ __align__(16) unsigned short samp_lds[WW * KLG];     // 12288B swizzled
    __shared__ __align__(8)  float2 geom[9 * 97];                   // 6984B (sy,sx)
    __shared__ float bias_lds[CC];

    const int bid = blockIdx.x;
    const int b   = bid / HH;
    const int h   = bid % HH;
    const int tid = threadIdx.x;
    const int r0  = min(max(h - 7, 0), HH - ROWS);   // window rows [r0, r0+14]

    const float* hrb = hr + (size_t)b * CC * PLANE;

    // --- plane-staging chunk geometry (4 x 16B chunks per thread) ---
    int pl_p[4], pl_off[4]; bool pl_v[4];
#pragma unroll
    for (int i = 0; i < 4; ++i) {
        int c = tid + i * 768;
        pl_v[i] = (c < NCHK);
        if (c >= NCHK) c = NCHK - 1;
        int p   = c / 360;            // 360 chunks per plane (15 rows * 24)
        int rem = c - p * 360;
        int r   = rem / 24;
        int x4  = rem - r * 24;
        pl_p[i]   = p;
        pl_off[i] = (r0 + r) * WW + x4 * 4;
    }
    // wgt chunks: c0 = tid; c1 = 768+tid (tid<256). 1024 chunks of 16B.
    const int woc0 = tid >> 3, wsl0 = tid & 7;
    const int woc1 = (768 + tid) >> 3, wsl1 = tid & 7;   // (768+tid)&7 == tid&7

    float4 plv[4], wv0, wv1;

#define ISSUE_G(G) { \
    int icb = (G) * GP; \
    _Pragma("unroll") \
    for (int i = 0; i < 4; ++i) { \
        int ic = min(icb + pl_p[i], CC - 1); \
        plv[i] = *reinterpret_cast<const float4*>(hrb + (size_t)ic * PLANE + pl_off[i]); \
    } \
    wv0 = *reinterpret_cast<const float4*>(wpad + ((size_t)woc0 * NG + (G)) * KLG + wsl0 * 8); \
    if (tid < 256) \
        wv1 = *reinterpret_cast<const float4*>(wpad + ((size_t)woc1 * NG + (G)) * KLG + wsl1 * 8); \
    }

#define WRITE_G() { \
    _Pragma("unroll") \
    for (int i = 0; i < 4; ++i) \
        if (pl_v[i]) *reinterpret_cast<float4*>((char*)planes_lds + (tid + i*768) * 16) = plv[i]; \
    *reinterpret_cast<float4*>((char*)wgt_lds + swzb(woc0, wsl0 * 16)) = wv0; \
    if (tid < 256) \
        *reinterpret_cast<float4*>((char*)wgt_lds + swzb(woc1, wsl1 * 16)) = wv1; \
    }

    // --- issue group 0 loads, then Phase A geometry (latency overlaps) ---
    ISSUE_G(0);

    for (int s = tid; s < 9 * WW; s += 768) {
        int tap = s / WW;
        int px  = s - tap * WW;
        int hw  = h * WW + px;
        float offy = b_off[2*tap], offx = b_off[2*tap + 1];
#pragma unroll
        for (int q = 0; q < NGRP; ++q) {
            offy += outp[((size_t)(b*CC + q*18 + 2*tap    )) * PLANE + hw];
            offx += outp[((size_t)(b*CC + q*18 + 2*tap + 1)) * PLANE + hw];
        }
        float sy = (float)h  + (float)(tap/3 - 1) + offy;
        float sx = (float)px + (float)(tap%3 - 1) + offx;
        geom[tap * 97 + px] = make_float2(sy, sx);
    }
    if (tid < CC) bias_lds[tid] = b_def[tid];

    const int lane = tid & 63;
    const int wid  = tid >> 6;        // 0..11
    const int ocg  = wid / 3;         // 0..3  (32 oc)
    const int pxg  = wid - ocg * 3;   // 0..2  (32 px)
    const int l15  = lane & 15;
    const int l4   = lane >> 4;
    const int bpx  = tid >> 3;        // build: px 0..95
    const int bkc  = tid & 7;         // build: k-chunk 0..7

    f32x4 acc[2][2];
#pragma unroll
    for (int mf = 0; mf < 2; ++mf)
#pragma unroll
        for (int nf = 0; nf < 2; ++nf)
            acc[mf][nf] = (f32x4){0.f, 0.f, 0.f, 0.f};

#define MFMA_G() { \
    _Pragma("unroll") \
    for (int ks = 0; ks < 2; ++ks) { \
        int kb = ks * 64 + l4 * 16; \
        bf16x8 afr0 = *reinterpret_cast<const bf16x8*>((char*)wgt_lds  + swzb(ocg*32 + l15,      kb)); \
        bf16x8 afr1 = *reinterpret_cast<const bf16x8*>((char*)wgt_lds  + swzb(ocg*32 + 16 + l15, kb)); \
        bf16x8 bfr0 = *reinterpret_cast<const bf16x8*>((char*)samp_lds + swzb(pxg*32 + l15,      kb)); \
        bf16x8 bfr1 = *reinterpret_cast<const bf16x8*>((char*)samp_lds + swzb(pxg*32 + 16 + l15, kb)); \
        acc[0][0] = __builtin_amdgcn_mfma_f32_16x16x32_bf16(afr0, bfr0, acc[0][0], 0, 0, 0); \
        acc[0][1] = __builtin_amdgcn_mfma_f32_16x16x32_bf16(afr0, bfr1, acc[0][1], 0, 0, 0); \
        acc[1][0] = __builtin_amdgcn_mfma_f32_16x16x32_bf16(afr1, bfr0, acc[1][0], 0, 0, 0); \
        acc[1][1] = __builtin_amdgcn_mfma_f32_16x16x32_bf16(afr1, bfr1, acc[1][1], 0, 0, 0); \
    } }

    for (int g = 0; g < NG; ++g) {
        if (g) MFMA_G();            // consumes samp/wgt of g-1
        __syncthreads();            // all waves done with g-1 LDS
        WRITE_G();                  // waits on vm loads issued for g
        __syncthreads();            // staging visible
        // ---- build samp(g): 8 samples (one px, 8 k-slots) per thread ----
        {
            const int icb = g * GP;
            unsigned pk[4];
#pragma unroll
            for (int j = 0; j < 8; ++j) {
                int kl    = bkc * 8 + j;
                int icoff = (kl * 57) >> 9;        // kl/9 for kl<64
                int tap   = kl - icoff * 9;
                int ic    = icb + icoff;
                float sv  = 0.f;
                if (kl != 63 && ic < CC) {
                    float2 s2 = geom[tap * 97 + bpx];
                    float sy = s2.x, sx = s2.y;
                    float y0f = floorf(sy), x0f = floorf(sx);
                    float dy = sy - y0f, dx = sx - x0f;
                    int y0 = (int)y0f, x0 = (int)x0f;
                    bool y0v = (unsigned)y0       < (unsigned)HH;
                    bool y1v = (unsigned)(y0 + 1) < (unsigned)HH;
                    bool x0v = (unsigned)x0       < (unsigned)WW;
                    bool x1v = (unsigned)(x0 + 1) < (unsigned)WW;
                    float ody = 1.f - dy, odx = 1.f - dx;
                    float w00 = (y0v && x0v) ? ody * odx : 0.f;
                    float w01 = (y0v && x1v) ? ody * dx  : 0.f;
                    float w10 = (y1v && x0v) ? dy  * odx : 0.f;
                    float w11 = (y1v && x1v) ? dy  * dx  : 0.f;
                    int y0c = min(max(y0, 0), HH-1), y1c = min(max(y0 + 1, 0), HH-1);
                    int x0c = min(max(x0, 0), WW-1), x1c = min(max(x0 + 1, 0), WW-1);
                    int ra = y0c - r0, rb = y1c - r0;
                    float v00, v01, v10, v11;
                    if (__builtin_expect(((unsigned)ra < (unsigned)ROWS) &
                                         ((unsigned)rb < (unsigned)ROWS), 1)) {
                        const float* pl2 = planes_lds + icoff * (ROWS * WW);
                        v00 = pl2[ra*WW + x0c]; v01 = pl2[ra*WW + x1c];
                        v10 = pl2[rb*WW + x0c]; v11 = pl2[rb*WW + x1c];
                    } else {                     // exact fallback (rare)
                        const float* gp2 = hrb + (size_t)ic * PLANE;
                        v00 = gp2[y0c*WW + x0c]; v01 = gp2[y0c*WW + x1c];
                        v10 = gp2[y1c*WW + x0c]; v11 = gp2[y1c*WW + x1c];
                    }
                    sv = fmaf(w00, v00, fmaf(w01, v01, fmaf(w10, v10, w11 * v11)));
                }
                unsigned us = (unsigned)__bfloat16_as_ushort(__float2bfloat16(sv));
                pk[j >> 1] = (j & 1) ? (pk[j >> 1] | (us << 16)) : us;
            }
            u32x4 pv = {pk[0], pk[1], pk[2], pk[3]};
            *reinterpret_cast<u32x4*>((char*)samp_lds + bpx * 128 + ((bkc * 16) ^ ((bpx & 7) << 4))) = pv;
        }
        if (g < NG - 1) ISSUE_G(g + 1);   // latency hides under next MFMA
        __syncthreads();                  // samp(g) visible
    }
    MFMA_G();                             // final group

    // ---- epilogue: bias + store ----
#pragma unroll
    for (int mf = 0; mf < 2; ++mf)
#pragma unroll
        for (int r = 0; r < 4; ++r) {
            int oc = ocg*32 + mf*16 + l4*4 + r;
            float bd = bias_lds[oc];
#pragma unroll
            for (int nf = 0; nf < 2; ++nf) {
                int px = pxg*32 + nf*16 + l15;
                outp[((size_t)(b*CC + oc)) * PLANE + h*WW + px] = acc[mf][nf][r] + bd;
            }
        }
#undef ISSUE_G
#undef WRITE_G
#undef MFMA_G
}

extern "C" void kernel_launch(void* const* d_in, const int* in_sizes, int n_in,
                              void* d_out, int out_size, void* d_ws, size_t ws_size,
                              hipStream_t stream)
{
    const float* lr    = (const float*)d_in[0];
    const float* hr    = (const float*)d_in[1];
    const float* w_off = (const float*)d_in[2];
    const float* b_off = (const float*)d_in[3];
    const float* w_def = (const float*)d_in[4];
    const float* b_def = (const float*)d_in[5];
    float* outp = (float*)d_out;
    unsigned short* wpad = (unsigned short*)d_ws;   // 128*19*64*2 = 311296 B

    wcvt_kernel<<<(CC*NG*KLG + 255)/256, 256, 0, stream>>>(w_def, wpad);
    offset_conv_kernel<<<4*36*NGRP, 256, 0, stream>>>(lr, hr, w_off, outp);
    deform_mfma_kernel<<<4*HH, 768, 0, stream>>>(hr, b_off, wpad, b_def, outp);
}

// Round 6
// 157.031 us; speedup vs baseline: 2.1994x; 2.0708x over previous
//
#include <hip/hip_runtime.h>
#include <hip/hip_bf16.h>

#define HH 96
#define WW 96
#define CC 128
#define C2 256
#define PLANE (HH*WW)          // 9216
#define NGRP 6                 // K1 channel groups (partials in d_out ch 0..107)
#define GP 8                   // ic per K2 group
#define NG 16                  // groups
#define KSG 72                 // real k-slots per group (9 taps * 8 ic)
#define ROWS 13                // staged rows per plane window
#define NPCHK (ROWS*WW)        // 1248 16B plane chunks per group

typedef __attribute__((ext_vector_type(8))) short bf16x8;
typedef __attribute__((ext_vector_type(4))) float f32x4;
typedef __attribute__((ext_vector_type(4))) unsigned int u32x4;

__device__ __forceinline__ int swz(int row, int byte_in_row) {
    return row * 128 + (byte_in_row ^ ((row & 7) << 4));
}

__device__ __forceinline__ void gload_lds16(const void* g, void* l) {
    __builtin_amdgcn_global_load_lds(
        (const __attribute__((address_space(1))) char*)g,
        (__attribute__((address_space(3))) char*)l, 16, 0, 0);
}

__device__ __forceinline__ unsigned pack2(float a, float b) {
    return (unsigned)__bfloat16_as_ushort(__float2bfloat16(a)) |
           ((unsigned)__bfloat16_as_ushort(__float2bfloat16(b)) << 16);
}

// ------------- Kernel 0a: w_def -> bf16 wpad[oc][g][72], kslot = tap*8+icoff -------
__global__ __launch_bounds__(256) void wcvt_kernel(const float* __restrict__ w,
                                                   unsigned short* __restrict__ o)
{
    int i = blockIdx.x * 256 + threadIdx.x;   // 128*16*72 = 147456
    if (i < CC * NG * KSG) {
        int oc = i / (NG * KSG);
        int r  = i - oc * (NG * KSG);
        int g  = r / KSG;
        int s  = r - g * KSG;
        int tap = s >> 3;
        int icoff = s & 7;
        o[i] = __bfloat16_as_ushort(__float2bfloat16(
            w[(size_t)(oc * CC + g * GP + icoff) * 9 + tap]));
    }
}

// ------------- Kernel 0b: hr -> bf16 ic-interleaved hrbf[b][g][hw][8] --------------
__global__ __launch_bounds__(256) void hrcvt_kernel(const float* __restrict__ hr,
                                                    unsigned short* __restrict__ o)
{
    int idx = blockIdx.x * 256 + threadIdx.x;     // 4*16*9216 = 589824, grid exact
    int hw = idx % PLANE;
    int t  = idx / PLANE;
    int g  = t & 15;
    int b  = t >> 4;
    const float* src = hr + ((size_t)(b * CC + g * GP)) * PLANE + hw;
    unsigned pk[4];
#pragma unroll
    for (int j = 0; j < 4; ++j)
        pk[j] = pack2(src[(size_t)(2*j) * PLANE], src[(size_t)(2*j+1) * PLANE]);
    u32x4 v = {pk[0], pk[1], pk[2], pk[3]};
    *reinterpret_cast<u32x4*>(o + (size_t)idx * 8) = v;
}

// ------------- Kernel 1: offset conv (partials into d_out ch 0..107) ---------------
__global__ __launch_bounds__(256) void offset_conv_kernel(
    const float* __restrict__ lr, const float* __restrict__ hr,
    const float* __restrict__ w_off, float* __restrict__ outp)
{
    __shared__ float tile[2][324];
    const int bid = blockIdx.x;
    const int q   = bid % NGRP;
    const int t   = bid / NGRP;
    const int b   = t / 36;
    const int rr  = t % 36;
    const int h0  = (rr / 6) * 16;
    const int w0  = (rr % 6) * 16;
    const int tid = threadIdx.x;
    const int py  = tid >> 4;
    const int px  = tid & 15;

    const int c0 = (C2 * q) / NGRP, c1 = (C2 * (q + 1)) / NGRP;
    const float* srcp = (q < 3) ? lr : hr;
    const int cofs = (q < 3) ? 0 : CC;

    int gy0 = h0 - 1 + tid / 18, gx0 = w0 - 1 + tid % 18;
    bool ok0 = (unsigned)gy0 < (unsigned)HH && (unsigned)gx0 < (unsigned)WW;
    int off0 = gy0 * WW + gx0;
    int j1 = tid + 256;
    int gy1 = h0 - 1 + j1 / 18, gx1 = w0 - 1 + j1 % 18;
    bool ok1 = (j1 < 324) && (unsigned)gy1 < (unsigned)HH && (unsigned)gx1 < (unsigned)WW;
    int off1 = gy1 * WW + gx1;

    float acc[18];
#pragma unroll
    for (int oc = 0; oc < 18; ++oc) acc[oc] = 0.f;

    const float* pl = srcp + (size_t)(b * CC + c0 - cofs) * PLANE;
    float p0 = ok0 ? pl[off0] : 0.f;
    float p1 = ok1 ? pl[off1] : 0.f;

    for (int c = c0; c < c1; ++c) {
        float* tb = tile[c & 1];
        tb[tid] = p0;
        if (j1 < 324) tb[j1] = p1;
        __syncthreads();
        if (c + 1 < c1) {
            const float* pn = srcp + (size_t)(b * CC + c + 1 - cofs) * PLANE;
            p0 = ok0 ? pn[off0] : 0.f;
            p1 = ok1 ? pn[off1] : 0.f;
        }
        float tv[9];
#pragma unroll
        for (int ky = 0; ky < 3; ++ky)
#pragma unroll
            for (int kx = 0; kx < 3; ++kx)
                tv[ky*3+kx] = tb[(py+ky)*18 + px + kx];
#pragma unroll
        for (int oc = 0; oc < 18; ++oc) {
            const float* wp = w_off + (size_t)(oc * C2 + c) * 9;   // uniform -> s_load
#pragma unroll
            for (int tap = 0; tap < 9; ++tap)
                acc[oc] = fmaf(wp[tap], tv[tap], acc[oc]);
        }
    }
#pragma unroll
    for (int oc = 0; oc < 18; ++oc)
        outp[((size_t)(b*CC + q*18 + oc)) * PLANE + (h0+py)*WW + (w0+px)] = acc[oc];
}

// ------------- Kernel 2: deformable conv, ic-interleaved LDS + bf16 MFMA -----------
// grid: 384 blocks (XCD-swizzled), 768 threads (12 waves: 4 ocg x 3 pxg)
template<bool HRBF>
__global__ __launch_bounds__(768, 6) void deform2_kernel(
    const float* __restrict__ hr, const unsigned short* __restrict__ hrbf,
    const float* __restrict__ b_off, const unsigned short* __restrict__ wpad,
    const float* __restrict__ b_def, float* __restrict__ outp)
{
    __shared__ __align__(16) unsigned short planes[ROWS*WW*GP];    // 19968B
    __shared__ __align__(16) unsigned short wgt0[CC*64];           // 16KB swz
    __shared__ __align__(16) unsigned short wgt1[CC*8];            // 2KB
    __shared__ __align__(16) unsigned short samp0[WW*64];          // 12KB swz
    __shared__ __align__(16) unsigned short samp1[WW*8];           // 1.5KB
    __shared__ __align__(8)  float2 geom[9*97];
    __shared__ float bias_lds[CC];

    const int rawb = blockIdx.x;
    const int bid  = (rawb & 7) * 48 + (rawb >> 3);   // XCD swizzle (384%8==0)
    const int b    = bid / HH;
    const int h    = bid % HH;
    const int tid  = threadIdx.x;
    const int r0   = min(max(h - 6, 0), HH - ROWS);

    const float* hrb = hr + (size_t)b * CC * PLANE;

    float4 wv0, wv1;
    const int wc0oc = tid / 9,        wc0s = tid % 9;          // chunk tid
    const int wc1oc = (tid + 768) / 9, wc1s = (tid + 768) % 9; // chunk tid+768 (tid<384)

#define ISSUE_WGT(G) { \
    wv0 = *reinterpret_cast<const float4*>(wpad + ((size_t)(wc0oc*NG + (G))*KSG + wc0s*8)); \
    if (tid < 384) \
        wv1 = *reinterpret_cast<const float4*>(wpad + ((size_t)(wc1oc*NG + (G))*KSG + wc1s*8)); \
    }
#define WRITE_WGT() { \
    if (wc0s < 8) *reinterpret_cast<float4*>((char*)wgt0 + swz(wc0oc, wc0s*16)) = wv0; \
    else          *reinterpret_cast<float4*>((char*)wgt1 + wc0oc*16) = wv0; \
    if (tid < 384) { \
        if (wc1s < 8) *reinterpret_cast<float4*>((char*)wgt0 + swz(wc1oc, wc1s*16)) = wv1; \
        else          *reinterpret_cast<float4*>((char*)wgt1 + wc1oc*16) = wv1; \
    } }

#define ISSUE_PLANES(G) { \
    const char* src = (const char*)(hrbf + ((size_t)(b*NG + (G))*PLANE + r0*WW)*8); \
    gload_lds16(src + tid*16, (char*)planes + tid*16); \
    if (tid < NPCHK - 768) \
        gload_lds16(src + (768 + tid)*16, (char*)planes + (768 + tid)*16); \
    }

#define STAGE_DIRECT(G) { \
    for (int p = tid; p < NPCHK; p += 768) { \
        int r = p / WW, x = p - (p / WW) * WW; \
        const float* s = hrb + (size_t)((G)*GP) * PLANE + (r0 + r)*WW + x; \
        unsigned pk[4]; \
        _Pragma("unroll") \
        for (int j = 0; j < 4; ++j) \
            pk[j] = pack2(s[(size_t)(2*j)*PLANE], s[(size_t)(2*j+1)*PLANE]); \
        u32x4 v = {pk[0], pk[1], pk[2], pk[3]}; \
        *reinterpret_cast<u32x4*>((char*)planes + p*16) = v; \
    } }

    // ---- prologue: start group-0 loads, then geometry ----
    if (HRBF) ISSUE_PLANES(0);
    ISSUE_WGT(0);

    for (int t = tid; t < 9 * WW; t += 768) {
        int tap = t / WW;
        int px  = t - tap * WW;
        int hw  = h * WW + px;
        float offy = b_off[2*tap], offx = b_off[2*tap + 1];
#pragma unroll
        for (int q = 0; q < NGRP; ++q) {
            offy += outp[((size_t)(b*CC + q*18 + 2*tap    )) * PLANE + hw];
            offx += outp[((size_t)(b*CC + q*18 + 2*tap + 1)) * PLANE + hw];
        }
        geom[tap*97 + px] = make_float2((float)h  + (float)(tap/3 - 1) + offy,
                                        (float)px + (float)(tap%3 - 1) + offx);
    }
    if (tid < CC) bias_lds[tid] = b_def[tid];

    const int lane = tid & 63;
    const int wid  = tid >> 6;
    const int ocg  = wid >> 2;          // 0..2?? no: 12 waves = 4 ocg * 3 pxg
    // correct decomposition: ocg 0..3, pxg 0..2
    const int ocg4 = wid / 3;
    const int pxg  = wid - ocg4 * 3;
    const int l15  = lane & 15;
    const int l4   = lane >> 4;
    (void)ocg;

    f32x4 acc[2][2];
#pragma unroll
    for (int mf = 0; mf < 2; ++mf)
#pragma unroll
        for (int nf = 0; nf < 2; ++nf)
            acc[mf][nf] = (f32x4){0.f, 0.f, 0.f, 0.f};

    const int rowA0 = ocg4*32 + l15, rowA1 = rowA0 + 16;
    const int rowB0 = pxg*32 + l15,  rowB1 = rowB0 + 16;
    const bf16x8 zf = {};

#define MFMA_G() { \
    _Pragma("unroll") \
    for (int ks = 0; ks < 2; ++ks) { \
        int kb = ks*64 + l4*16; \
        bf16x8 a0 = *reinterpret_cast<const bf16x8*>((char*)wgt0 + swz(rowA0, kb)); \
        bf16x8 a1 = *reinterpret_cast<const bf16x8*>((char*)wgt0 + swz(rowA1, kb)); \
        bf16x8 b0 = *reinterpret_cast<const bf16x8*>((char*)samp0 + swz(rowB0, kb)); \
        bf16x8 b1 = *reinterpret_cast<const bf16x8*>((char*)samp0 + swz(rowB1, kb)); \
        acc[0][0] = __builtin_amdgcn_mfma_f32_16x16x32_bf16(a0, b0, acc[0][0], 0, 0, 0); \
        acc[0][1] = __builtin_amdgcn_mfma_f32_16x16x32_bf16(a0, b1, acc[0][1], 0, 0, 0); \
        acc[1][0] = __builtin_amdgcn_mfma_f32_16x16x32_bf16(a1, b0, acc[1][0], 0, 0, 0); \
        acc[1][1] = __builtin_amdgcn_mfma_f32_16x16x32_bf16(a1, b1, acc[1][1], 0, 0, 0); \
    } \
    { /* k-step 2: 8 real kslots in l4==0 lanes, A zeroed elsewhere */ \
        bf16x8 a0 = *reinterpret_cast<const bf16x8*>((char*)wgt1 + rowA0*16); \
        bf16x8 a1 = *reinterpret_cast<const bf16x8*>((char*)wgt1 + rowA1*16); \
        bf16x8 b0 = *reinterpret_cast<const bf16x8*>((char*)samp1 + rowB0*16); \
        bf16x8 b1 = *reinterpret_cast<const bf16x8*>((char*)samp1 + rowB1*16); \
        if (l4) { a0 = zf; a1 = zf; } \
        acc[0][0] = __builtin_amdgcn_mfma_f32_16x16x32_bf16(a0, b0, acc[0][0], 0, 0, 0); \
        acc[0][1] = __builtin_amdgcn_mfma_f32_16x16x32_bf16(a0, b1, acc[0][1], 0, 0, 0); \
        acc[1][0] = __builtin_amdgcn_mfma_f32_16x16x32_bf16(a1, b0, acc[1][0], 0, 0, 0); \
        acc[1][1] = __builtin_amdgcn_mfma_f32_16x16x32_bf16(a1, b1, acc[1][1], 0, 0, 0); \
    } }

    for (int g = 0; g < NG; ++g) {
        if (g) MFMA_G();
        __syncthreads();          // MFMA(g-1) done; planes(g) loads drained
        WRITE_WGT();
        if (!HRBF) STAGE_DIRECT(g);
        __syncthreads();          // wgt + planes visible
        // ---- build samp(g): item = (tap, px); pass 1 taps 0..7, pass 2 tap 8 ----
        for (int it = tid; it < 9 * WW; it += 768) {
            int tap = it / WW;
            int px  = it - tap * WW;
            float2 s2 = geom[tap*97 + px];
            float sy = s2.x, sx = s2.y;
            float y0f = floorf(sy), x0f = floorf(sx);
            float dy = sy - y0f, dx = sx - x0f;
            int y0 = (int)y0f, x0 = (int)x0f;
            bool y0v = (unsigned)y0       < (unsigned)HH;
            bool y1v = (unsigned)(y0 + 1) < (unsigned)HH;
            bool x0v = (unsigned)x0       < (unsigned)WW;
            bool x1v = (unsigned)(x0 + 1) < (unsigned)WW;
            float ody = 1.f - dy, odx = 1.f - dx;
            float w00 = (y0v && x0v) ? ody*odx : 0.f;
            float w01 = (y0v && x1v) ? ody*dx  : 0.f;
            float w10 = (y1v && x0v) ? dy*odx  : 0.f;
            float w11 = (y1v && x1v) ? dy*dx   : 0.f;
            int y0c = min(max(y0, 0), HH-1), y1c = min(max(y0+1, 0), HH-1);
            int x0c = min(max(x0, 0), WW-1), x1c = min(max(x0+1, 0), WW-1);
            float sv[GP];
            bool ng = (y0v && (unsigned)(y0 - r0) >= (unsigned)ROWS) ||
                      (y1v && (unsigned)(y1c - r0) >= (unsigned)ROWS);
            if (__builtin_expect(!ng, 1)) {
                int ra = min(max(y0c - r0, 0), ROWS-1);
                int rb = min(max(y1c - r0, 0), ROWS-1);
                u32x4 q00 = *reinterpret_cast<const u32x4*>((char*)planes + (ra*WW + x0c)*16);
                u32x4 q01 = *reinterpret_cast<const u32x4*>((char*)planes + (ra*WW + x1c)*16);
                u32x4 q10 = *reinterpret_cast<const u32x4*>((char*)planes + (rb*WW + x0c)*16);
                u32x4 q11 = *reinterpret_cast<const u32x4*>((char*)planes + (rb*WW + x1c)*16);
#pragma unroll
                for (int j = 0; j < 4; ++j) {
                    float a00 = __uint_as_float(q00[j] << 16), b00 = __uint_as_float(q00[j] & 0xffff0000u);
                    float a01 = __uint_as_float(q01[j] << 16), b01 = __uint_as_float(q01[j] & 0xffff0000u);
                    float a10 = __uint_as_float(q10[j] << 16), b10 = __uint_as_float(q10[j] & 0xffff0000u);
                    float a11 = __uint_as_float(q11[j] << 16), b11 = __uint_as_float(q11[j] & 0xffff0000u);
                    sv[2*j]   = fmaf(w00, a00, fmaf(w01, a01, fmaf(w10, a10, w11*a11)));
                    sv[2*j+1] = fmaf(w00, b00, fmaf(w01, b01, fmaf(w10, b10, w11*b11)));
                }
            } else {   // exact rare fallback from global f32
                const float* base = hrb + (size_t)(g*GP) * PLANE;
#pragma unroll
                for (int j = 0; j < GP; ++j) {
                    const float* p = base + (size_t)j * PLANE;
                    sv[j] = fmaf(w00, p[y0c*WW + x0c], fmaf(w01, p[y0c*WW + x1c],
                            fmaf(w10, p[y1c*WW + x0c], w11 * p[y1c*WW + x1c])));
                }
            }
            unsigned pk0 = pack2(sv[0], sv[1]), pk1 = pack2(sv[2], sv[3]);
            unsigned pk2 = pack2(sv[4], sv[5]), pk3 = pack2(sv[6], sv[7]);
            u32x4 pv = {pk0, pk1, pk2, pk3};
            if (tap < 8)
                *reinterpret_cast<u32x4*>((char*)samp0 + swz(px, tap*16)) = pv;
            else
                *reinterpret_cast<u32x4*>((char*)samp1 + px*16) = pv;
        }
        __syncthreads();          // samp(g) visible; planes reads done
        if (g < NG - 1) {
            if (HRBF) ISSUE_PLANES(g + 1);   // lands before next top barrier
            ISSUE_WGT(g + 1);
        }
    }
    MFMA_G();

    // ---- epilogue ----
#pragma unroll
    for (int mf = 0; mf < 2; ++mf)
#pragma unroll
        for (int r = 0; r < 4; ++r) {
            int oc = ocg4*32 + mf*16 + l4*4 + r;
            float bd = bias_lds[oc];
#pragma unroll
            for (int nf = 0; nf < 2; ++nf) {
                int px = pxg*32 + nf*16 + l15;
                outp[((size_t)(b*CC + oc)) * PLANE + h*WW + px] = acc[mf][nf][r] + bd;
            }
        }
#undef ISSUE_WGT
#undef WRITE_WGT
#undef ISSUE_PLANES
#undef STAGE_DIRECT
#undef MFMA_G
}

extern "C" void kernel_launch(void* const* d_in, const int* in_sizes, int n_in,
                              void* d_out, int out_size, void* d_ws, size_t ws_size,
                              hipStream_t stream)
{
    const float* lr    = (const float*)d_in[0];
    const float* hr    = (const float*)d_in[1];
    const float* w_off = (const float*)d_in[2];
    const float* b_off = (const float*)d_in[3];
    const float* w_def = (const float*)d_in[4];
    const float* b_def = (const float*)d_in[5];
    float* outp = (float*)d_out;

    const size_t wpad_bytes = (size_t)CC * NG * KSG * 2;           // 294912
    const size_t hrbf_bytes = (size_t)4 * NG * PLANE * GP * 2;     // 9437184
    unsigned short* wpad = (unsigned short*)d_ws;
    unsigned short* hrbf = (unsigned short*)((char*)d_ws + wpad_bytes);
    bool use_hrbf = ws_size >= wpad_bytes + hrbf_bytes;

    wcvt_kernel<<<(CC*NG*KSG + 255)/256, 256, 0, stream>>>(w_def, wpad);
    if (use_hrbf)
        hrcvt_kernel<<<(4*NG*PLANE)/256, 256, 0, stream>>>(hr, hrbf);
    offset_conv_kernel<<<4*36*NGRP, 256, 0, stream>>>(lr, hr, w_off, outp);
    if (use_hrbf)
        deform2_kernel<true><<<4*HH, 768, 0, stream>>>(hr, hrbf, b_off, wpad, b_def, outp);
    else
        deform2_kernel<false><<<4*HH, 768, 0, stream>>>(hr, hrbf, b_off, wpad, b_def, outp);
}

// Round 7
// 115.218 us; speedup vs baseline: 2.9976x; 1.3629x over previous
//
#include <hip/hip_runtime.h>
#include <hip/hip_bf16.h>

#define HH 96
#define WW 96
#define CC 128
#define C2 256
#define PLANE (HH*WW)          // 9216
#define NGRP 6                 // fallback K1 channel groups
#define GP 8                   // ic per group
#define NG 16                  // hr groups
#define KSG 72                 // k-slots per group (9 taps * 8 ic)
#define ROWS 13                // deform staged rows per plane window
#define NPCHK (ROWS*WW)        // 1248 16B plane chunks per group

typedef __attribute__((ext_vector_type(8))) short bf16x8;
typedef __attribute__((ext_vector_type(4))) float f32x4;
typedef __attribute__((ext_vector_type(4))) unsigned int u32x4;

__device__ __forceinline__ int swz(int row, int byte_in_row) {
    return row * 128 + (byte_in_row ^ ((row & 7) << 4));
}

__device__ __forceinline__ void gload_lds16(const void* g, void* l) {
    __builtin_amdgcn_global_load_lds(
        (const __attribute__((address_space(1))) char*)g,
        (__attribute__((address_space(3))) char*)l, 16, 0, 0);
}

__device__ __forceinline__ unsigned pack2(float a, float b) {
    return (unsigned)__bfloat16_as_ushort(__float2bfloat16(a)) |
           ((unsigned)__bfloat16_as_ushort(__float2bfloat16(b)) << 16);
}

// ------------- Kernel 0a: w_def -> bf16 wpad[oc][g][72], kslot = tap*8+icoff -------
__global__ __launch_bounds__(256) void wcvt_kernel(const float* __restrict__ w,
                                                   unsigned short* __restrict__ o)
{
    int i = blockIdx.x * 256 + threadIdx.x;   // 128*16*72 = 147456
    if (i < CC * NG * KSG) {
        int oc = i / (NG * KSG);
        int r  = i - oc * (NG * KSG);
        int g  = r / KSG;
        int s  = r - g * KSG;
        int tap = s >> 3;
        int icoff = s & 7;
        o[i] = __bfloat16_as_ushort(__float2bfloat16(
            w[(size_t)(oc * CC + g * GP + icoff) * 9 + tap]));
    }
}

// ------------- Kernel 0b: plane set -> bf16 ic-interleaved [b][g16][hw][8] ---------
__global__ __launch_bounds__(256) void cvt8_kernel(const float* __restrict__ src0,
                                                   unsigned short* __restrict__ o)
{
    int idx = blockIdx.x * 256 + threadIdx.x;     // 4*16*9216 grid exact
    int hw = idx % PLANE;
    int t  = idx / PLANE;
    int g  = t & 15;
    int b  = t >> 4;
    const float* src = src0 + ((size_t)(b * CC + g * GP)) * PLANE + hw;
    unsigned pk[4];
#pragma unroll
    for (int j = 0; j < 4; ++j)
        pk[j] = pack2(src[(size_t)(2*j) * PLANE], src[(size_t)(2*j+1) * PLANE]);
    u32x4 v = {pk[0], pk[1], pk[2], pk[3]};
    *reinterpret_cast<u32x4*>(o + (size_t)idx * 8) = v;
}

// ------------- Kernel 0c: w_off -> bf16 wop[32oc][32g][72], kslot = tap*8+icoff ----
__global__ __launch_bounds__(256) void woffcvt_kernel(const float* __restrict__ w,
                                                      unsigned short* __restrict__ o)
{
    int i = blockIdx.x * 256 + threadIdx.x;   // 32*32*72 = 73728
    if (i < 32 * 32 * KSG) {
        int oc = i / (32 * KSG);
        int r  = i - oc * (32 * KSG);
        int g  = r / KSG;
        int s  = r - g * KSG;
        int tap = s >> 3;
        int icoff = s & 7;
        int c = g * 8 + icoff;
        float v = (oc < 18) ? w[(size_t)(oc * C2 + c) * 9 + tap] : 0.f;
        o[i] = __bfloat16_as_ushort(__float2bfloat16(v));
    }
}

// ------------- Kernel 1 (fallback): fp32 offset conv, partials into d_out ----------
__global__ __launch_bounds__(256) void offset_conv_kernel(
    const float* __restrict__ lr, const float* __restrict__ hr,
    const float* __restrict__ w_off, float* __restrict__ outp)
{
    __shared__ float tile[2][324];
    const int bid = blockIdx.x;
    const int q   = bid % NGRP;
    const int t   = bid / NGRP;
    const int b   = t / 36;
    const int rr  = t % 36;
    const int h0  = (rr / 6) * 16;
    const int w0  = (rr % 6) * 16;
    const int tid = threadIdx.x;
    const int py  = tid >> 4;
    const int px  = tid & 15;

    const int c0 = (C2 * q) / NGRP, c1 = (C2 * (q + 1)) / NGRP;
    const float* srcp = (q < 3) ? lr : hr;
    const int cofs = (q < 3) ? 0 : CC;

    int gy0 = h0 - 1 + tid / 18, gx0 = w0 - 1 + tid % 18;
    bool ok0 = (unsigned)gy0 < (unsigned)HH && (unsigned)gx0 < (unsigned)WW;
    int off0 = gy0 * WW + gx0;
    int j1 = tid + 256;
    int gy1 = h0 - 1 + j1 / 18, gx1 = w0 - 1 + j1 % 18;
    bool ok1 = (j1 < 324) && (unsigned)gy1 < (unsigned)HH && (unsigned)gx1 < (unsigned)WW;
    int off1 = gy1 * WW + gx1;

    float acc[18];
#pragma unroll
    for (int oc = 0; oc < 18; ++oc) acc[oc] = 0.f;

    const float* pl = srcp + (size_t)(b * CC + c0 - cofs) * PLANE;
    float p0 = ok0 ? pl[off0] : 0.f;
    float p1 = ok1 ? pl[off1] : 0.f;

    for (int c = c0; c < c1; ++c) {
        float* tb = tile[c & 1];
        tb[tid] = p0;
        if (j1 < 324) tb[j1] = p1;
        __syncthreads();
        if (c + 1 < c1) {
            const float* pn = srcp + (size_t)(b * CC + c + 1 - cofs) * PLANE;
            p0 = ok0 ? pn[off0] : 0.f;
            p1 = ok1 ? pn[off1] : 0.f;
        }
        float tv[9];
#pragma unroll
        for (int ky = 0; ky < 3; ++ky)
#pragma unroll
            for (int kx = 0; kx < 3; ++kx)
                tv[ky*3+kx] = tb[(py+ky)*18 + px + kx];
#pragma unroll
        for (int oc = 0; oc < 18; ++oc) {
            const float* wp = w_off + (size_t)(oc * C2 + c) * 9;
#pragma unroll
            for (int tap = 0; tap < 9; ++tap)
                acc[oc] = fmaf(wp[tap], tv[tap], acc[oc]);
        }
    }
#pragma unroll
    for (int oc = 0; oc < 18; ++oc)
        outp[((size_t)(b*CC + q*18 + oc)) * PLANE + (h0+py)*WW + (w0+px)] = acc[oc];
}

// ------------- Kernel 1': offset conv as bf16 MFMA gather-GEMM ---------------------
// grid: 384 blocks (XCD-swizzled), 768 threads (12 waves: 2 ocg x 6 pxg)
__global__ __launch_bounds__(768, 6) void offset_mfma_kernel(
    const unsigned short* __restrict__ lrbf, const unsigned short* __restrict__ hrbf,
    const unsigned short* __restrict__ wop, const float* __restrict__ b_off,
    float* __restrict__ offw)
{
    __shared__ __align__(16) unsigned short planes[3*WW*8];   // 4608B
    __shared__ __align__(16) unsigned short wgt0[32*64];      // 4KB swz
    __shared__ __align__(16) unsigned short wgt1[32*8];       // 512B
    __shared__ __align__(16) unsigned short samp0[WW*64];     // 12KB swz
    __shared__ __align__(16) unsigned short samp1[WW*8];      // 1.5KB

    const int rawb = blockIdx.x;
    const int bid  = (rawb & 7) * 48 + (rawb >> 3);   // XCD swizzle
    const int b    = bid / HH;
    const int h    = bid % HH;
    const int tid  = threadIdx.x;

    // wgt chunks: 32 oc * 9 = 288 16B chunks (prefix-active: tid<288)
    const int woc = tid / 9, wsl = tid % 9;
    // plane chunks: 3 rows * 96 = 288; rows clamped (keeps lane prefix full)
    const int pri = tid / 96, ppx = tid - (tid / 96) * 96;
    const int prow = min(max(h - 1 + pri, 0), HH - 1);

    float4 wv;

#define ISSUE_P(G2) { \
    if (tid < 288) { \
        const unsigned short* base = ((G2) < 16 ? lrbf : hrbf); \
        const unsigned short* src = base + \
            ((size_t)((b*16 + ((G2) & 15))) * PLANE + prow*WW + ppx) * 8; \
        gload_lds16(src, (char*)planes + tid*16); \
    } }
#define ISSUE_W(G2) { \
    if (tid < 288) \
        wv = *reinterpret_cast<const float4*>(wop + ((size_t)(woc*32 + (G2)))*KSG + wsl*8); \
    }
#define WRITE_W() { \
    if (tid < 288) { \
        if (wsl < 8) *reinterpret_cast<float4*>((char*)wgt0 + swz(woc, wsl*16)) = wv; \
        else         *reinterpret_cast<float4*>((char*)wgt1 + woc*16) = wv; \
    } }

    ISSUE_P(0);
    ISSUE_W(0);

    const int lane = tid & 63;
    const int wid  = tid >> 6;
    const int ocg  = wid / 6;          // 0..1
    const int pxg  = wid - ocg * 6;    // 0..5
    const int l15  = lane & 15;
    const int l4   = lane >> 4;
    const int rowA = ocg*16 + l15;
    const int rowB = pxg*16 + l15;
    const bf16x8 zf = {};

    f32x4 acc = (f32x4){0.f, 0.f, 0.f, 0.f};

#define MFMA_G() { \
    _Pragma("unroll") \
    for (int ks = 0; ks < 2; ++ks) { \
        int kb = ks*64 + l4*16; \
        bf16x8 a = *reinterpret_cast<const bf16x8*>((char*)wgt0 + swz(rowA, kb)); \
        bf16x8 bb = *reinterpret_cast<const bf16x8*>((char*)samp0 + swz(rowB, kb)); \
        acc = __builtin_amdgcn_mfma_f32_16x16x32_bf16(a, bb, acc, 0, 0, 0); \
    } \
    { \
        bf16x8 a = *reinterpret_cast<const bf16x8*>((char*)wgt1 + rowA*16); \
        bf16x8 bb = *reinterpret_cast<const bf16x8*>((char*)samp1 + rowB*16); \
        if (l4) a = zf; \
        acc = __builtin_amdgcn_mfma_f32_16x16x32_bf16(a, bb, acc, 0, 0, 0); \
    } }

    for (int g2 = 0; g2 < 32; ++g2) {
        if (g2) MFMA_G();
        __syncthreads();          // MFMA(g2-1) LDS reads done; planes(g2) gloads drained
        WRITE_W();
        // ---- build samp(g2): pure 16B LDS copies with conv bounds ----
        {
            int it = tid;                       // item 1 (all threads)
#pragma unroll
            for (int pass = 0; pass < 2; ++pass) {
                if (pass == 0 || tid < 96) {
                    int tap = it / WW;
                    int px  = it - tap * WW;
                    int ky  = tap / 3 - 1, kx = tap % 3 - 1;
                    int row = h + ky, x = px + kx;
                    u32x4 v = {0u, 0u, 0u, 0u};
                    if ((unsigned)row < (unsigned)HH && (unsigned)x < (unsigned)WW)
                        v = *reinterpret_cast<const u32x4*>((char*)planes + ((ky+1)*WW + x)*16);
                    if (tap < 8)
                        *reinterpret_cast<u32x4*>((char*)samp0 + swz(px, tap*16)) = v;
                    else
                        *reinterpret_cast<u32x4*>((char*)samp1 + px*16) = v;
                }
                it = tid + 768;                 // item 2 (tid<96)
            }
        }
        __syncthreads();          // wgt+samp visible; planes reads done
        if (g2 < 31) { ISSUE_P(g2 + 1); ISSUE_W(g2 + 1); }
    }
    MFMA_G();

    // ---- epilogue ----
#pragma unroll
    for (int r = 0; r < 4; ++r) {
        int oc = ocg*16 + l4*4 + r;
        if (oc < 18)
            offw[((size_t)(b*18 + oc)) * PLANE + h*WW + pxg*16 + l15] = acc[r] + b_off[oc];
    }
#undef ISSUE_P
#undef ISSUE_W
#undef WRITE_W
#undef MFMA_G
}

// ------------- Kernel 2: deformable conv, ic-interleaved LDS + bf16 MFMA -----------
// grid: 384 blocks (XCD-swizzled), 768 threads (12 waves: 4 ocg x 3 pxg)
template<bool HRBF, bool OFFWS>
__global__ __launch_bounds__(768, 6) void deform2_kernel(
    const float* __restrict__ hr, const unsigned short* __restrict__ hrbf,
    const float* __restrict__ b_off, const unsigned short* __restrict__ wpad,
    const float* __restrict__ b_def, const float* __restrict__ offw,
    float* __restrict__ outp)
{
    __shared__ __align__(16) unsigned short planes[ROWS*WW*GP];    // 19968B
    __shared__ __align__(16) unsigned short wgt0[CC*64];           // 16KB swz
    __shared__ __align__(16) unsigned short wgt1[CC*8];            // 2KB
    __shared__ __align__(16) unsigned short samp0[WW*64];          // 12KB swz
    __shared__ __align__(16) unsigned short samp1[WW*8];           // 1.5KB
    __shared__ __align__(8)  float2 geom[9*97];
    __shared__ float bias_lds[CC];

    const int rawb = blockIdx.x;
    const int bid  = (rawb & 7) * 48 + (rawb >> 3);   // XCD swizzle (384%8==0)
    const int b    = bid / HH;
    const int h    = bid % HH;
    const int tid  = threadIdx.x;
    const int r0   = min(max(h - 6, 0), HH - ROWS);

    const float* hrb = hr + (size_t)b * CC * PLANE;

    float4 wv0, wv1;
    const int wc0oc = tid / 9,        wc0s = tid % 9;
    const int wc1oc = (tid + 768) / 9, wc1s = (tid + 768) % 9;

#define ISSUE_WGT(G) { \
    wv0 = *reinterpret_cast<const float4*>(wpad + ((size_t)(wc0oc*NG + (G))*KSG + wc0s*8)); \
    if (tid < 384) \
        wv1 = *reinterpret_cast<const float4*>(wpad + ((size_t)(wc1oc*NG + (G))*KSG + wc1s*8)); \
    }
#define WRITE_WGT() { \
    if (wc0s < 8) *reinterpret_cast<float4*>((char*)wgt0 + swz(wc0oc, wc0s*16)) = wv0; \
    else          *reinterpret_cast<float4*>((char*)wgt1 + wc0oc*16) = wv0; \
    if (tid < 384) { \
        if (wc1s < 8) *reinterpret_cast<float4*>((char*)wgt0 + swz(wc1oc, wc1s*16)) = wv1; \
        else          *reinterpret_cast<float4*>((char*)wgt1 + wc1oc*16) = wv1; \
    } }

#define ISSUE_PLANES(G) { \
    const char* src = (const char*)(hrbf + ((size_t)(b*NG + (G))*PLANE + r0*WW)*8); \
    gload_lds16(src + tid*16, (char*)planes + tid*16); \
    if (tid < NPCHK - 768) \
        gload_lds16(src + (768 + tid)*16, (char*)planes + (768 + tid)*16); \
    }

#define STAGE_DIRECT(G) { \
    for (int p = tid; p < NPCHK; p += 768) { \
        int r = p / WW, x = p - (p / WW) * WW; \
        const float* s = hrb + (size_t)((G)*GP) * PLANE + (r0 + r)*WW + x; \
        unsigned pk[4]; \
        _Pragma("unroll") \
        for (int j = 0; j < 4; ++j) \
            pk[j] = pack2(s[(size_t)(2*j)*PLANE], s[(size_t)(2*j+1)*PLANE]); \
        u32x4 v = {pk[0], pk[1], pk[2], pk[3]}; \
        *reinterpret_cast<u32x4*>((char*)planes + p*16) = v; \
    } }

    if (HRBF) ISSUE_PLANES(0);
    ISSUE_WGT(0);

    for (int t = tid; t < 9 * WW; t += 768) {
        int tap = t / WW;
        int px  = t - tap * WW;
        int hw  = h * WW + px;
        float offy, offx;
        if (OFFWS) {
            offy = offw[((size_t)(b*18 + 2*tap    )) * PLANE + hw];
            offx = offw[((size_t)(b*18 + 2*tap + 1)) * PLANE + hw];
        } else {
            offy = b_off[2*tap]; offx = b_off[2*tap + 1];
#pragma unroll
            for (int q = 0; q < NGRP; ++q) {
                offy += outp[((size_t)(b*CC + q*18 + 2*tap    )) * PLANE + hw];
                offx += outp[((size_t)(b*CC + q*18 + 2*tap + 1)) * PLANE + hw];
            }
        }
        geom[tap*97 + px] = make_float2((float)h  + (float)(tap/3 - 1) + offy,
                                        (float)px + (float)(tap%3 - 1) + offx);
    }
    if (tid < CC) bias_lds[tid] = b_def[tid];

    const int lane = tid & 63;
    const int wid  = tid >> 6;
    const int ocg4 = wid / 3;
    const int pxg  = wid - ocg4 * 3;
    const int l15  = lane & 15;
    const int l4   = lane >> 4;

    f32x4 acc[2][2];
#pragma unroll
    for (int mf = 0; mf < 2; ++mf)
#pragma unroll
        for (int nf = 0; nf < 2; ++nf)
            acc[mf][nf] = (f32x4){0.f, 0.f, 0.f, 0.f};

    const int rowA0 = ocg4*32 + l15, rowA1 = rowA0 + 16;
    const int rowB0 = pxg*32 + l15,  rowB1 = rowB0 + 16;
    const bf16x8 zf = {};

#define MFMA_G() { \
    _Pragma("unroll") \
    for (int ks = 0; ks < 2; ++ks) { \
        int kb = ks*64 + l4*16; \
        bf16x8 a0 = *reinterpret_cast<const bf16x8*>((char*)wgt0 + swz(rowA0, kb)); \
        bf16x8 a1 = *reinterpret_cast<const bf16x8*>((char*)wgt0 + swz(rowA1, kb)); \
        bf16x8 b0 = *reinterpret_cast<const bf16x8*>((char*)samp0 + swz(rowB0, kb)); \
        bf16x8 b1 = *reinterpret_cast<const bf16x8*>((char*)samp0 + swz(rowB1, kb)); \
        acc[0][0] = __builtin_amdgcn_mfma_f32_16x16x32_bf16(a0, b0, acc[0][0], 0, 0, 0); \
        acc[0][1] = __builtin_amdgcn_mfma_f32_16x16x32_bf16(a0, b1, acc[0][1], 0, 0, 0); \
        acc[1][0] = __builtin_amdgcn_mfma_f32_16x16x32_bf16(a1, b0, acc[1][0], 0, 0, 0); \
        acc[1][1] = __builtin_amdgcn_mfma_f32_16x16x32_bf16(a1, b1, acc[1][1], 0, 0, 0); \
    } \
    { \
        bf16x8 a0 = *reinterpret_cast<const bf16x8*>((char*)wgt1 + rowA0*16); \
        bf16x8 a1 = *reinterpret_cast<const bf16x8*>((char*)wgt1 + rowA1*16); \
        bf16x8 b0 = *reinterpret_cast<const bf16x8*>((char*)samp1 + rowB0*16); \
        bf16x8 b1 = *reinterpret_cast<const bf16x8*>((char*)samp1 + rowB1*16); \
        if (l4) { a0 = zf; a1 = zf; } \
        acc[0][0] = __builtin_amdgcn_mfma_f32_16x16x32_bf16(a0, b0, acc[0][0], 0, 0, 0); \
        acc[0][1] = __builtin_amdgcn_mfma_f32_16x16x32_bf16(a0, b1, acc[0][1], 0, 0, 0); \
        acc[1][0] = __builtin_amdgcn_mfma_f32_16x16x32_bf16(a1, b0, acc[1][0], 0, 0, 0); \
        acc[1][1] = __builtin_amdgcn_mfma_f32_16x16x32_bf16(a1, b1, acc[1][1], 0, 0, 0); \
    } }

    for (int g = 0; g < NG; ++g) {
        if (g) MFMA_G();
        __syncthreads();
        WRITE_WGT();
        if (!HRBF) STAGE_DIRECT(g);
        __syncthreads();
        for (int it = tid; it < 9 * WW; it += 768) {
            int tap = it / WW;
            int px  = it - tap * WW;
            float2 s2 = geom[tap*97 + px];
            float sy = s2.x, sx = s2.y;
            float y0f = floorf(sy), x0f = floorf(sx);
            float dy = sy - y0f, dx = sx - x0f;
            int y0 = (int)y0f, x0 = (int)x0f;
            bool y0v = (unsigned)y0       < (unsigned)HH;
            bool y1v = (unsigned)(y0 + 1) < (unsigned)HH;
            bool x0v = (unsigned)x0       < (unsigned)WW;
            bool x1v = (unsigned)(x0 + 1) < (unsigned)WW;
            float ody = 1.f - dy, odx = 1.f - dx;
            float w00 = (y0v && x0v) ? ody*odx : 0.f;
            float w01 = (y0v && x1v) ? ody*dx  : 0.f;
            float w10 = (y1v && x0v) ? dy*odx  : 0.f;
            float w11 = (y1v && x1v) ? dy*dx   : 0.f;
            int y0c = min(max(y0, 0), HH-1), y1c = min(max(y0+1, 0), HH-1);
            int x0c = min(max(x0, 0), WW-1), x1c = min(max(x0+1, 0), WW-1);
            float sv[GP];
            bool ng = (y0v && (unsigned)(y0 - r0) >= (unsigned)ROWS) ||
                      (y1v && (unsigned)(y1c - r0) >= (unsigned)ROWS);
            if (__builtin_expect(!ng, 1)) {
                int ra = min(max(y0c - r0, 0), ROWS-1);
                int rb = min(max(y1c - r0, 0), ROWS-1);
                u32x4 q00 = *reinterpret_cast<const u32x4*>((char*)planes + (ra*WW + x0c)*16);
                u32x4 q01 = *reinterpret_cast<const u32x4*>((char*)planes + (ra*WW + x1c)*16);
                u32x4 q10 = *reinterpret_cast<const u32x4*>((char*)planes + (rb*WW + x0c)*16);
                u32x4 q11 = *reinterpret_cast<const u32x4*>((char*)planes + (rb*WW + x1c)*16);
#pragma unroll
                for (int j = 0; j < 4; ++j) {
                    float a00 = __uint_as_float(q00[j] << 16), b00 = __uint_as_float(q00[j] & 0xffff0000u);
                    float a01 = __uint_as_float(q01[j] << 16), b01 = __uint_as_float(q01[j] & 0xffff0000u);
                    float a10 = __uint_as_float(q10[j] << 16), b10 = __uint_as_float(q10[j] & 0xffff0000u);
                    float a11 = __uint_as_float(q11[j] << 16), b11 = __uint_as_float(q11[j] & 0xffff0000u);
                    sv[2*j]   = fmaf(w00, a00, fmaf(w01, a01, fmaf(w10, a10, w11*a11)));
                    sv[2*j+1] = fmaf(w00, b00, fmaf(w01, b01, fmaf(w10, b10, w11*b11)));
                }
            } else {
                const float* base = hrb + (size_t)(g*GP) * PLANE;
#pragma unroll
                for (int j = 0; j < GP; ++j) {
                    const float* p = base + (size_t)j * PLANE;
                    sv[j] = fmaf(w00, p[y0c*WW + x0c], fmaf(w01, p[y0c*WW + x1c],
                            fmaf(w10, p[y1c*WW + x0c], w11 * p[y1c*WW + x1c])));
                }
            }
            unsigned pk0 = pack2(sv[0], sv[1]), pk1 = pack2(sv[2], sv[3]);
            unsigned pk2 = pack2(sv[4], sv[5]), pk3 = pack2(sv[6], sv[7]);
            u32x4 pv = {pk0, pk1, pk2, pk3};
            if (tap < 8)
                *reinterpret_cast<u32x4*>((char*)samp0 + swz(px, tap*16)) = pv;
            else
                *reinterpret_cast<u32x4*>((char*)samp1 + px*16) = pv;
        }
        __syncthreads();
        if (g < NG - 1) {
            if (HRBF) ISSUE_PLANES(g + 1);
            ISSUE_WGT(g + 1);
        }
    }
    MFMA_G();

#pragma unroll
    for (int mf = 0; mf < 2; ++mf)
#pragma unroll
        for (int r = 0; r < 4; ++r) {
            int oc = ocg4*32 + mf*16 + l4*4 + r;
            float bd = bias_lds[oc];
#pragma unroll
            for (int nf = 0; nf < 2; ++nf) {
                int px = pxg*32 + nf*16 + l15;
                outp[((size_t)(b*CC + oc)) * PLANE + h*WW + px] = acc[mf][nf][r] + bd;
            }
        }
#undef ISSUE_WGT
#undef WRITE_WGT
#undef ISSUE_PLANES
#undef STAGE_DIRECT
#undef MFMA_G
}

extern "C" void kernel_launch(void* const* d_in, const int* in_sizes, int n_in,
                              void* d_out, int out_size, void* d_ws, size_t ws_size,
                              hipStream_t stream)
{
    const float* lr    = (const float*)d_in[0];
    const float* hr    = (const float*)d_in[1];
    const float* w_off = (const float*)d_in[2];
    const float* b_off = (const float*)d_in[3];
    const float* w_def = (const float*)d_in[4];
    const float* b_def = (const float*)d_in[5];
    float* outp = (float*)d_out;

    const size_t wpad_b = (size_t)CC * NG * KSG * 2;            // 294912
    const size_t hrbf_b = (size_t)4 * NG * PLANE * GP * 2;      // 9437184
    const size_t lrbf_b = hrbf_b;
    const size_t woff_b = (size_t)32 * 32 * KSG * 2;            // 147456
    const size_t offw_b = (size_t)4 * 18 * PLANE * 4;           // 2654208

    unsigned short* wpad = (unsigned short*)d_ws;
    unsigned short* hrbf = (unsigned short*)((char*)d_ws + wpad_b);
    unsigned short* lrbf = (unsigned short*)((char*)d_ws + wpad_b + hrbf_b);
    unsigned short* wop  = (unsigned short*)((char*)d_ws + wpad_b + hrbf_b + lrbf_b);
    float*          offw = (float*)((char*)d_ws + wpad_b + hrbf_b + lrbf_b + woff_b);

    const bool full    = ws_size >= wpad_b + hrbf_b + lrbf_b + woff_b + offw_b;
    const bool use_hrbf = ws_size >= wpad_b + hrbf_b;

    wcvt_kernel<<<(CC*NG*KSG + 255)/256, 256, 0, stream>>>(w_def, wpad);
    if (use_hrbf)
        cvt8_kernel<<<(4*NG*PLANE)/256, 256, 0, stream>>>(hr, hrbf);

    if (full) {
        cvt8_kernel<<<(4*NG*PLANE)/256, 256, 0, stream>>>(lr, lrbf);
        woffcvt_kernel<<<(32*32*KSG + 255)/256, 256, 0, stream>>>(w_off, wop);
        offset_mfma_kernel<<<4*HH, 768, 0, stream>>>(lrbf, hrbf, wop, b_off, offw);
        deform2_kernel<true, true><<<4*HH, 768, 0, stream>>>(
            hr, hrbf, b_off, wpad, b_def, offw, outp);
    } else {
        offset_conv_kernel<<<4*36*NGRP, 256, 0, stream>>>(lr, hr, w_off, outp);
        if (use_hrbf)
            deform2_kernel<true, false><<<4*HH, 768, 0, stream>>>(
                hr, hrbf, b_off, wpad, b_def, offw, outp);
        else
            deform2_kernel<false, false><<<4*HH, 768, 0, stream>>>(
                hr, hrbf, b_off, wpad, b_def, offw, outp);
    }
}